// Round 5
// baseline (233.983 us; speedup 1.0000x reference)
//
#include <hip/hip_runtime.h>

// InvRT: out[m,n,b,l] = -(e0 + e1*tanh((z - e2)*e3)), params from eta_fault[Mask[m,l]]
// z (8,64,512,128) f32. HBM-bound streaming op; floor ~42us @ 6.3 TB/s combined.
// R4: R0-R3 all collapsed to ~32 VGPR interleaved load/compute/store (~80us,
// 2.5 TB/s) -- the scheduler sinks burst loads to cut register pressure, and
// the interleaved form makes every load-wait also wait on store acks (shared
// vmcnt). Pin the burst with sched_barrier(0): 8 loads issue back-to-back and
// stay live across the barrier; all stores follow all loads.

#define M_DIM 8
#define L_DIM 128
#define PER_M 4194304        // N*B*L floats per m
#define BLOCKS_PER_M 512
#define THREADS 256
#define PER_BLOCK 8192       // PER_M / BLOCKS_PER_M floats
#define DEPTH 8              // float4s per thread, all in flight
#define STRIDE (THREADS * 4)

typedef float f32x4 __attribute__((ext_vector_type(4)));

__device__ __forceinline__ float fast_tanh(float x) {
    // tanh(x) = 1 - 2/(1 + exp2(x * 2*log2e)); saturates correctly at +-1.
    float t = __builtin_amdgcn_exp2f(x * 2.8853900817779268f);
    float r = __builtin_amdgcn_rcpf(1.0f + t);
    return __builtin_fmaf(-2.0f, r, 1.0f);
}

__global__ __launch_bounds__(THREADS, 1) void invrt_kernel(
    const float* __restrict__ z,
    const float* __restrict__ eta_fault,
    const int*  __restrict__ mask,
    float* __restrict__ out)
{
    const int tid   = threadIdx.x;
    const int bid   = blockIdx.x;
    const int m     = bid >> 9;        // 512 blocks per m
    const int chunk = bid & 511;

    // Thread owns l = l0..l0+3 for every iteration (iteration stride 1024 and
    // block base are multiples of L=128, so the l-phase is loop-invariant).
    const int l0 = (tid & 31) * 4;

    float a0[4], a1[4], a2[4], a3[4];
#pragma unroll
    for (int j = 0; j < 4; ++j) {
        const int row = mask[m * L_DIM + l0 + j];     // 0..18
        const f32x4 e = *reinterpret_cast<const f32x4*>(eta_fault + row * 4);
        a0[j] = -e.x;   // -e0
        a1[j] = -e.y;   // -e1
        a2[j] = e.z;    //  e2
        a3[j] = e.w;    //  e3
    }

    const long long base = (long long)m * PER_M + (long long)chunk * PER_BLOCK + tid * 4;
    const float* zp = z + base;
    float*       op = out + base;

    // Burst: ALL loads issue before the barrier; the scheduler cannot sink
    // them past sched_barrier(0), so 8 loads/wave are in flight at once and
    // no load-wait can be coupled to a store ack (stores all come later).
    f32x4 v[DEPTH];
#pragma unroll
    for (int j = 0; j < DEPTH; ++j)
        v[j] = *reinterpret_cast<const f32x4*>(zp + j * STRIDE);

    __builtin_amdgcn_sched_barrier(0);   // hard fence: nothing crosses

#pragma unroll
    for (int j = 0; j < DEPTH; ++j) {
        f32x4 o;
        o.x = __builtin_fmaf(a1[0], fast_tanh((v[j].x - a2[0]) * a3[0]), a0[0]);
        o.y = __builtin_fmaf(a1[1], fast_tanh((v[j].y - a2[1]) * a3[1]), a0[1]);
        o.z = __builtin_fmaf(a1[2], fast_tanh((v[j].z - a2[2]) * a3[2]), a0[2]);
        o.w = __builtin_fmaf(a1[3], fast_tanh((v[j].w - a2[3]) * a3[3]), a0[3]);
        // out is never re-read: nontemporal store keeps z's L3 residency.
        __builtin_nontemporal_store(o, reinterpret_cast<f32x4*>(op + j * STRIDE));
    }
}

extern "C" void kernel_launch(void* const* d_in, const int* in_sizes, int n_in,
                              void* d_out, int out_size, void* d_ws, size_t ws_size,
                              hipStream_t stream) {
    const float* z   = (const float*)d_in[0];
    const float* eta = (const float*)d_in[1];
    const int*   msk = (const int*)d_in[2];
    float*       out = (float*)d_out;

    dim3 grid(M_DIM * BLOCKS_PER_M);   // 4096 blocks, 2 generations/CU
    dim3 block(THREADS);
    invrt_kernel<<<grid, block, 0, stream>>>(z, eta, msk, out);
}